// Round 2
// baseline (221.079 us; speedup 1.0000x reference)
//
#include <hip/hip_runtime.h>
#include <hip/hip_fp16.h>

// Problem constants: B=4, S=1024, HID=1024, NH=16, HD=64
#define B_    4
#define S_    1024
#define HID_  1024
#define NH_   16
#define HD_   64

#define LOG2E 1.44269504f
#define PSTR  40   // padded LDS row stride in halves (80 B): b128 reads 2-way max

typedef _Float16 half8 __attribute__((ext_vector_type(8)));
typedef float f32x4 __attribute__((ext_vector_type(4)));

__device__ __forceinline__ half8 cvt8(float4 a, float4 b) {
    half8 h;
    h[0] = (_Float16)a.x; h[1] = (_Float16)a.y;
    h[2] = (_Float16)a.z; h[3] = (_Float16)a.w;
    h[4] = (_Float16)b.x; h[5] = (_Float16)b.y;
    h[6] = (_Float16)b.z; h[7] = (_Float16)b.w;
    return h;
}

// Raw barrier that does NOT drain vmcnt: LDS ops must be complete (writes
// published) before any wave crosses; in-flight global prefetch loads stay
// outstanding across it (T4: never vmcnt(0) in the main loop).
__device__ __forceinline__ void lds_barrier() {
    asm volatile("s_waitcnt lgkmcnt(0)" ::: "memory");
    __builtin_amdgcn_s_barrier();
    __builtin_amdgcn_sched_barrier(0);   // nothing hoists above the barrier
}

// ---------------------------------------------------------------------------
// Fused q/k projection (z: 0=q, 1=k). fp32 in, register cvt to fp16 during
// LDS staging. out = A @ W^T + bias in MFMA-fragment-friendly layouts:
//   Q' : [b, h, qtile=s/16, kplane=d/8, s%16, d%8]
//   K' : [b, h, kplane=d/8, s, d%8]
// 128x128 tile, 512 thr = 8 waves (2m x 4n), BK=32.
// v3: raw-barrier pipeline — global prefetch (depth 2) spans a full
//     iteration across the barrier; only lgkm drains per iter.
// ---------------------------------------------------------------------------
__global__ __launch_bounds__(512) void proj_qk_f16(
    const float* __restrict__ query, const float* __restrict__ Wq,
    const float* __restrict__ bq, _Float16* __restrict__ Oq,
    const float* __restrict__ key, const float* __restrict__ Wk,
    const float* __restrict__ bk, _Float16* __restrict__ Ok)
{
    // XCD-chunked swizzle (512 blocks % 8 == 0 -> bijective).
    const int f  = blockIdx.x + 8 * blockIdx.y + 256 * blockIdx.z;
    const int w2 = (f & 7) * 64 + (f >> 3);
    const int bx = w2 & 7, by = (w2 >> 3) & 31, bz = w2 >> 8;

    const float* A    = bz ? key : query;
    const float* Wm   = bz ? Wk  : Wq;
    const float* bias = bz ? bk  : bq;
    _Float16* Co      = bz ? Ok  : Oq;

    __shared__ _Float16 Al[2][128 * PSTR];   // 2 x 10 KB
    __shared__ _Float16 Bl[2][128 * PSTR];   // 2 x 10 KB   (40 KB total)

    const int tid  = threadIdx.x;
    const int wv   = tid >> 6;
    const int lane = tid & 63;
    const int l15  = lane & 15;
    const int quad = lane >> 4;
    const int wm   = wv & 1, wn = wv >> 1;            // wn 0..3
    const int m0   = by * 128, n0 = bx * 128;
    const int sr   = tid >> 2;                        // 0..127
    const int sc   = (tid & 3) * 8;                   // 8-float chunks

    const float* ap = A  + (long)(m0 + sr) * HID_ + sc;
    const float* bp = Wm + (long)(n0 + sr) * HID_ + sc;

    f32x4 acc[4][2];
#pragma unroll
    for (int i = 0; i < 4; i++)
#pragma unroll
        for (int j = 0; j < 2; j++) acc[i][j] = (f32x4){0.f, 0.f, 0.f, 0.f};

    // ---- prologue: tile 0 -> LDS buf0; tile 1 -> regs ----
    float4 a0 = *(const float4*)ap,       a1 = *(const float4*)(ap + 4);
    float4 b0 = *(const float4*)bp,       b1 = *(const float4*)(bp + 4);
    *(half8*)&Al[0][sr * PSTR + sc] = cvt8(a0, a1);
    *(half8*)&Bl[0][sr * PSTR + sc] = cvt8(b0, b1);
    a0 = *(const float4*)(ap + 32); a1 = *(const float4*)(ap + 36);
    b0 = *(const float4*)(bp + 32); b1 = *(const float4*)(bp + 36);
    lds_barrier();

    // invariant entering iter kt: buf[p] = tile kt, regs = tile kt+32
#pragma unroll 2
    for (int kt = 0; kt < HID_; kt += 32) {
        const int p = (kt >> 5) & 1;

        // issue tile kt+64 loads: consumed one FULL iteration later (the
        // raw barrier below does not drain vmcnt).
        float4 na0 = a0, na1 = a1, nb0 = b0, nb1 = b1;
        if (kt + 64 < HID_) {
            na0 = *(const float4*)(ap + kt + 64);
            na1 = *(const float4*)(ap + kt + 68);
            nb0 = *(const float4*)(bp + kt + 64);
            nb1 = *(const float4*)(bp + kt + 68);
        }

        // frag reads from current buffer
        half8 af[4], bfm[2];
#pragma unroll
        for (int i = 0; i < 4; i++)
            af[i] = *(const half8*)(&Al[p][(wm * 64 + i * 16 + l15) * PSTR + quad * 8]);
#pragma unroll
        for (int j = 0; j < 2; j++)
            bfm[j] = *(const half8*)(&Bl[p][(wn * 32 + j * 16 + l15) * PSTR + quad * 8]);

        // stage tile kt+32 (regs loaded last iter; per-reg vmcnt wait only)
        if (kt + 32 < HID_) {
            *(half8*)&Al[p ^ 1][sr * PSTR + sc] = cvt8(a0, a1);
            *(half8*)&Bl[p ^ 1][sr * PSTR + sc] = cvt8(b0, b1);
        }

#pragma unroll
        for (int i = 0; i < 4; i++)
#pragma unroll
            for (int j = 0; j < 2; j++)
                acc[i][j] = __builtin_amdgcn_mfma_f32_16x16x32_f16(
                    af[i], bfm[j], acc[i][j], 0, 0, 0);

        lds_barrier();
        a0 = na0; a1 = na1; b0 = nb0; b1 = nb1;
    }

    const int isQ = (bz == 0);
#pragma unroll
    for (int j = 0; j < 2; j++) {
        int col = n0 + wn * 32 + j * 16 + l15;
        float bv = bias[col];
        int h = col >> 6, d = col & 63, p = d >> 3, jj = d & 7;
#pragma unroll
        for (int i = 0; i < 4; i++) {
            int row = m0 + wm * 64 + i * 16 + quad * 4;
            int bb = row >> 10, ss = row & 1023;   // tiles never straddle 1024
            long base;
            if (isQ)
                base = ((((long)(bb * NH_ + h) * 64 + (ss >> 4)) * 8 + p) * 16
                        + (ss & 15)) * 8 + jj;
            else
                base = (((long)(bb * NH_ + h) * 8 + p) * 1024 + ss) * 8 + jj;
            // both layouts advance by 8 elements per +1 row
#pragma unroll
            for (int r = 0; r < 4; r++)
                Co[base + r * 8] = (_Float16)(acc[i][j][r] + bv);
        }
    }
}

// ---------------------------------------------------------------------------
// MFMA attention, head-split z=4.  Fragment loads from the dense Q'/K'
// layouts: A-load = 1KB contiguous per wave, B-load = 4x256B segments.
// No-max softmax (scores bounded, exp2 + folded log2e), ONE barrier per head.
// ---------------------------------------------------------------------------
__global__ __launch_bounds__(512) void attn_psum_f16(
    const _Float16* __restrict__ qb,   // Q' [B,NH,64,8,16,8]
    const _Float16* __restrict__ kb,   // K' [B,NH,8,S,8]
    const float* __restrict__ mask,    // [B,S]
    _Float16* __restrict__ P)          // 4 x [B,S,S] fp16 quarters
{
    const int b    = blockIdx.y;
    const int qt   = blockIdx.x;       // q-tile (16 rows)
    const int q0   = qt * 16;
    const int hz   = blockIdx.z;       // head group 0..3
    const int tid  = threadIdx.x;
    const int w    = tid >> 6;         // wave 0..7
    const int lane = tid & 63;
    const int l15  = lane & 15;
    const int quad = lane >> 4;

    __shared__ float redS[2][16][8];

    const float SC = 0.125f * LOG2E;

    float mreg[8];
#pragma unroll
    for (int t = 0; t < 8; t++)
        mreg[t] = mask[b * S_ + t * 128 + w * 16 + l15] * LOG2E;

    f32x4 acc[8];
#pragma unroll
    for (int t = 0; t < 8; t++) acc[t] = (f32x4){0.f, 0.f, 0.f, 0.f};

    for (int ii = 0; ii < 4; ii++) {
        const int h = hz * 4 + ii;
        const _Float16* qh = qb + ((long)(b * NH_ + h) * 64 + qt) * 1024;
        const _Float16* kh = kb + (long)(b * NH_ + h) * 8192 * 8;

        // A frags: Q'[qt][plane=quad(+4)][l15][j] — dense wave loads
        half8 a0 = *(const half8*)(qh + quad * 128 + l15 * 8);
        half8 a1 = *(const half8*)(qh + (quad + 4) * 128 + l15 * 8);

        f32x4 s[8];
#pragma unroll
        for (int cc = 0; cc < 8; cc++) {
            const int key = cc * 128 + w * 16 + l15;
            half8 b0 = *(const half8*)(kh + (long)quad * 8192 + key * 8);
            half8 b1 = *(const half8*)(kh + (long)(quad + 4) * 8192 + key * 8);
            f32x4 c = (f32x4){0.f, 0.f, 0.f, 0.f};
            c = __builtin_amdgcn_mfma_f32_16x16x32_f16(a0, b0, c, 0, 0, 0);
            c = __builtin_amdgcn_mfma_f32_16x16x32_f16(a1, b1, c, 0, 0, 0);
            s[cc] = c;
        }

        // ---- exp2 + row-sum (no max pass; one barrier per head) ----
        const int p = ii & 1;
        float sm[4] = {0.f, 0.f, 0.f, 0.f};
#pragma unroll
        for (int t = 0; t < 8; t++)
#pragma unroll
            for (int r = 0; r < 4; r++) {
                float pr = exp2f(s[t][r] * SC + mreg[t]);
                s[t][r] = pr;
                sm[r] += pr;
            }
#pragma unroll
        for (int off = 1; off < 16; off <<= 1)
#pragma unroll
            for (int r = 0; r < 4; r++) sm[r] += __shfl_xor(sm[r], off);
        if (l15 == 0)
#pragma unroll
            for (int r = 0; r < 4; r++) redS[p][quad * 4 + r][w] = sm[r];
        __syncthreads();

#pragma unroll
        for (int r = 0; r < 4; r++) {
            float4 v0 = *(float4*)&redS[p][quad * 4 + r][0];
            float4 v1 = *(float4*)&redS[p][quad * 4 + r][4];
            float tot = (v0.x + v0.y + v0.z + v0.w) + (v1.x + v1.y + v1.z + v1.w);
            float inv = 1.f / tot;
#pragma unroll
            for (int t = 0; t < 8; t++) acc[t][r] += s[t][r] * inv;
        }
    }

    _Float16* prow = P + (long)hz * ((long)B_ * S_ * S_) + (long)(b * S_ + q0) * S_;
#pragma unroll
    for (int t = 0; t < 8; t++)
#pragma unroll
        for (int r = 0; r < 4; r++) {
            int row = quad * 4 + r;
            prow[(long)row * S_ + t * 128 + w * 16 + l15] = (_Float16)acc[t][r];
        }
}

// ---------------------------------------------------------------------------
// v_transpose: Vt[b,h,s] = (fp16) V[b,s,h].  4096 blocks x 256 thr.
// (P-quarter summing moved into pv_f16's A-staging.)
// ---------------------------------------------------------------------------
__global__ __launch_bounds__(256) void v_transpose(
    const float* __restrict__ V, _Float16* __restrict__ Vt)
{
    __shared__ float t[32][33];
    const int x  = blockIdx.x;
    const int b  = x >> 10;
    const int s0 = ((x >> 5) & 31) * 32;
    const int h0 = (x & 31) * 32;
    const int tx = threadIdx.x & 31, ty = threadIdx.x >> 5;
#pragma unroll
    for (int rr = 0; rr < 4; rr++) {
        int s = s0 + ty + rr * 8;
        t[ty + rr * 8][tx] = V[((long)b * S_ + s) * HID_ + h0 + tx];
    }
    __syncthreads();
#pragma unroll
    for (int rr = 0; rr < 4; rr++) {
        int h = h0 + ty + rr * 8;
        Vt[((long)b * HID_ + h) * S_ + s0 + tx] = (_Float16)t[tx][ty + rr * 8];
    }
}

// ---------------------------------------------------------------------------
// PV GEMM: out = ((P0+P1+P2+P3) @ Vt^T) / NH, fp16 MFMA, fp32 out.
// Quarter-sum fused into A-staging (packed fp16 adds).  128m x 64n tile,
// 256 thr = 4 waves (2m x 2n), BK=32, raw-barrier pipeline like proj.
// ---------------------------------------------------------------------------
__global__ __launch_bounds__(256) void pv_f16(
    const _Float16* __restrict__ P,    // 4 x [B,S,S] fp16 quarters
    const _Float16* __restrict__ Vt,   // [B,HID,S] fp16
    float* __restrict__ out)           // [B,S,HID] fp32
{
    // XCD-chunked swizzle (512 blocks): each XCD gets 4 m-panels x all n of
    // one batch -> A panels (1 MB) + Vt (2 MB) fit its L2.
    const int f  = blockIdx.x + 16 * blockIdx.y + 128 * blockIdx.z;
    const int w2 = (f & 7) * 64 + (f >> 3);
    const int bx = w2 & 15, by = (w2 >> 4) & 7, bz = w2 >> 7;

    const int b = bz;
    const long QS = (long)B_ * S_ * S_;
    const _Float16* A  = P  + (long)b * S_ * S_;
    const _Float16* Bm = Vt + (long)b * HID_ * S_;

    __shared__ _Float16 Al[2][128 * PSTR];  // 2 x 10 KB
    __shared__ _Float16 Bl[2][64 * PSTR];   // 2 x 5 KB

    const int tid  = threadIdx.x;
    const int wv   = tid >> 6;
    const int lane = tid & 63;
    const int l15  = lane & 15;
    const int quad = lane >> 4;
    const int wm   = wv & 1, wn = wv >> 1;
    const int m0   = by * 128, n0 = bx * 64;
    const int sr   = tid >> 2;                       // 0..63
    const int sc   = (tid & 3) * 8;

    f32x4 acc[4][2];
#pragma unroll
    for (int i = 0; i < 4; i++)
#pragma unroll
        for (int j = 0; j < 2; j++) acc[i][j] = (f32x4){0.f, 0.f, 0.f, 0.f};

    half8 ca[2][4], cb;

    // ---- prologue: tile 0 -> LDS buf0 (summed); tile 1 -> regs ----
#pragma unroll
    for (int r = 0; r < 2; r++) {
        const _Float16* p0 = A + (long)(m0 + r * 64 + sr) * S_ + sc;
        half8 x0 = *(const half8*)(p0);
        half8 x1 = *(const half8*)(p0 + QS);
        half8 x2 = *(const half8*)(p0 + 2 * QS);
        half8 x3 = *(const half8*)(p0 + 3 * QS);
        *(half8*)&Al[0][(r * 64 + sr) * PSTR + sc] = (x0 + x1) + (x2 + x3);
    }
    *(half8*)&Bl[0][sr * PSTR + sc] = *(const half8*)(Bm + (long)(n0 + sr) * S_ + sc);
#pragma unroll
    for (int r = 0; r < 2; r++)
#pragma unroll
        for (int q = 0; q < 4; q++)
            ca[r][q] = *(const half8*)(A + (long)q * QS + (long)(m0 + r * 64 + sr) * S_ + 32 + sc);
    cb = *(const half8*)(Bm + (long)(n0 + sr) * S_ + 32 + sc);
    lds_barrier();

    // invariant entering iter kt: buf[p] = tile kt (summed), regs = tile kt+32
#pragma unroll 2
    for (int kt = 0; kt < S_; kt += 32) {
        const int p = (kt >> 5) & 1;

        half8 na[2][4], nb;
        if (kt + 64 < S_) {
#pragma unroll
            for (int r = 0; r < 2; r++)
#pragma unroll
                for (int q = 0; q < 4; q++)
                    na[r][q] = *(const half8*)(A + (long)q * QS
                        + (long)(m0 + r * 64 + sr) * S_ + kt + 64 + sc);
            nb = *(const half8*)(Bm + (long)(n0 + sr) * S_ + kt + 64 + sc);
        } else {
#pragma unroll
            for (int r = 0; r < 2; r++)
#pragma unroll
                for (int q = 0; q < 4; q++) na[r][q] = ca[r][q];
            nb = cb;
        }

        half8 af[4], bfm[2];
#pragma unroll
        for (int i = 0; i < 4; i++)
            af[i] = *(const half8*)(&Al[p][(wm * 64 + i * 16 + l15) * PSTR + quad * 8]);
#pragma unroll
        for (int j = 0; j < 2; j++)
            bfm[j] = *(const half8*)(&Bl[p][(wn * 32 + j * 16 + l15) * PSTR + quad * 8]);

        if (kt + 32 < S_) {
#pragma unroll
            for (int r = 0; r < 2; r++) {
                half8 s = (ca[r][0] + ca[r][1]) + (ca[r][2] + ca[r][3]);  // v_pk_add_f16
                *(half8*)&Al[p ^ 1][(r * 64 + sr) * PSTR + sc] = s;
            }
            *(half8*)&Bl[p ^ 1][sr * PSTR + sc] = cb;
        }

#pragma unroll
        for (int i = 0; i < 4; i++)
#pragma unroll
            for (int j = 0; j < 2; j++)
                acc[i][j] = __builtin_amdgcn_mfma_f32_16x16x32_f16(
                    af[i], bfm[j], acc[i][j], 0, 0, 0);

        lds_barrier();
#pragma unroll
        for (int r = 0; r < 2; r++)
#pragma unroll
            for (int q = 0; q < 4; q++) ca[r][q] = na[r][q];
        cb = nb;
    }

    const float alpha = 1.f / NH_;
#pragma unroll
    for (int i = 0; i < 4; i++) {
        int row = m0 + wm * 64 + i * 16 + quad * 4;
#pragma unroll
        for (int j = 0; j < 2; j++) {
            int col = n0 + wn * 32 + j * 16 + l15;
#pragma unroll
            for (int r = 0; r < 4; r++)
                out[(long)(b * S_ + row + r) * HID_ + col] = acc[i][j][r] * alpha;
        }
    }
}

// ---------------------------------------------------------------------------
extern "C" void kernel_launch(void* const* d_in, const int* in_sizes, int n_in,
                              void* d_out, int out_size, void* d_ws, size_t ws_size,
                              hipStream_t stream)
{
    const float* mask  = (const float*)d_in[0];
    const float* query = (const float*)d_in[1];
    const float* key   = (const float*)d_in[2];
    const float* value = (const float*)d_in[3];
    const float* Wq    = (const float*)d_in[4];
    const float* bq    = (const float*)d_in[5];
    const float* Wk    = (const float*)d_in[6];
    const float* bk    = (const float*)d_in[7];
    float* out = (float*)d_out;

    // Workspace (48 MiB, hand-offs between SEQUENTIAL dispatches only):
    //  [ 0, 8M): qbuf (Q' proj out)  -> after attn: Vt
    //  [ 8,16M): kbuf (K' proj out)
    //  [16,48M): P quarters (4 x 8M) -> read directly by pv (sum fused)
    char* ws = (char*)d_ws;
    const long MB = 1l << 20;
    _Float16* qbuf = (_Float16*)(ws);
    _Float16* kbuf = (_Float16*)(ws + 8 * MB);
    _Float16* Pq   = (_Float16*)(ws + 16 * MB);
    _Float16* Vt   = (_Float16*)(ws);             // reuses qbuf after attn

    // 1) fused q/k projection (fp32 in, inline cvt, fragment-layout fp16 out)
    proj_qk_f16<<<dim3(HID_ / 128, (B_ * S_) / 128, 2), dim3(512), 0, stream>>>(
        query, Wq, bq, qbuf, key, Wk, bk, kbuf);

    // 2) attention, head-split z=4 -> P quarters
    attn_psum_f16<<<dim3(S_ / 16, B_, 4), dim3(512), 0, stream>>>(
        qbuf, kbuf, mask, Pq);

    // 3) V -> fp16 transpose -> Vt
    v_transpose<<<dim3(4096), dim3(256), 0, stream>>>(value, Vt);

    // 4) out = (sum_q Pq) @ Vt^T / NH  (quarter-sum fused into staging)
    pv_f16<<<dim3(HID_ / 64, S_ / 128, B_), dim3(256), 0, stream>>>(Pq, Vt, out);
}

// Round 4
// 196.112 us; speedup vs baseline: 1.1273x; 1.1273x over previous
//
#include <hip/hip_runtime.h>
#include <hip/hip_fp16.h>

// Problem constants: B=4, S=1024, HID=1024, NH=16, HD=64
#define B_    4
#define S_    1024
#define HID_  1024
#define NH_   16
#define HD_   64

#define LOG2E 1.44269504f
#define PSTR  40   // padded LDS row stride in halves (80 B): b128 reads 2-way max

typedef _Float16 half8 __attribute__((ext_vector_type(8)));
typedef float f32x4 __attribute__((ext_vector_type(4)));

__device__ __forceinline__ half8 cvt8(float4 a, float4 b) {
    half8 h;
    h[0] = (_Float16)a.x; h[1] = (_Float16)a.y;
    h[2] = (_Float16)a.z; h[3] = (_Float16)a.w;
    h[4] = (_Float16)b.x; h[5] = (_Float16)b.y;
    h[6] = (_Float16)b.z; h[7] = (_Float16)b.w;
    return h;
}

// Single-instruction 2^x. exp2f without -ffast-math emits a guarded libm
// sequence (~8 VALU inst); our arguments are bounded (|x| << 126) so the
// raw instruction is sufficient.
__device__ __forceinline__ float fexp2(float x) {
#if __has_builtin(__builtin_amdgcn_exp2f)
    return __builtin_amdgcn_exp2f(x);
#else
    float r;
    // s_nop covers the trans-op wait-state hazard for the external consumer
    asm("v_exp_f32 %0, %1\n\ts_nop 0" : "=v"(r) : "v"(x));
    return r;
#endif
}

// Raw barrier that does NOT drain vmcnt: LDS ops must be complete (writes
// published) before any wave crosses; in-flight global prefetch loads stay
// outstanding across it (T4: never vmcnt(0) in the main loop).
__device__ __forceinline__ void lds_barrier() {
    asm volatile("s_waitcnt lgkmcnt(0)" ::: "memory");
    __builtin_amdgcn_s_barrier();
    __builtin_amdgcn_sched_barrier(0);   // nothing hoists above the barrier
}

// ---------------------------------------------------------------------------
// Fused q/k projection (z: 0=q, 1=k). fp32 in, register cvt to fp16 during
// LDS staging. out = A @ W^T + bias in MFMA-fragment-friendly layouts:
//   Q' : [b, h, qtile=s/16, kplane=d/8, s%16, d%8]
//   K' : [b, h, kplane=d/8, s, d%8]
// 128x128 tile, 512 thr = 8 waves (2m x 4n), BK=32, raw-barrier depth-2
// pipeline, XCD-chunked swizzle.
// ---------------------------------------------------------------------------
__global__ __launch_bounds__(512) void proj_qk_f16(
    const float* __restrict__ query, const float* __restrict__ Wq,
    const float* __restrict__ bq, _Float16* __restrict__ Oq,
    const float* __restrict__ key, const float* __restrict__ Wk,
    const float* __restrict__ bk, _Float16* __restrict__ Ok)
{
    // XCD-chunked swizzle (512 blocks % 8 == 0 -> bijective).
    const int f  = blockIdx.x + 8 * blockIdx.y + 256 * blockIdx.z;
    const int w2 = (f & 7) * 64 + (f >> 3);
    const int bx = w2 & 7, by = (w2 >> 3) & 31, bz = w2 >> 8;

    const float* A    = bz ? key : query;
    const float* Wm   = bz ? Wk  : Wq;
    const float* bias = bz ? bk  : bq;
    _Float16* Co      = bz ? Ok  : Oq;

    __shared__ _Float16 Al[2][128 * PSTR];   // 2 x 10 KB
    __shared__ _Float16 Bl[2][128 * PSTR];   // 2 x 10 KB   (40 KB total)

    const int tid  = threadIdx.x;
    const int wv   = tid >> 6;
    const int lane = tid & 63;
    const int l15  = lane & 15;
    const int quad = lane >> 4;
    const int wm   = wv & 1, wn = wv >> 1;            // wn 0..3
    const int m0   = by * 128, n0 = bx * 128;
    const int sr   = tid >> 2;                        // 0..127
    const int sc   = (tid & 3) * 8;                   // 8-float chunks

    const float* ap = A  + (long)(m0 + sr) * HID_ + sc;
    const float* bp = Wm + (long)(n0 + sr) * HID_ + sc;

    f32x4 acc[4][2];
#pragma unroll
    for (int i = 0; i < 4; i++)
#pragma unroll
        for (int j = 0; j < 2; j++) acc[i][j] = (f32x4){0.f, 0.f, 0.f, 0.f};

    // ---- prologue: tile 0 -> LDS buf0; tile 1 -> regs ----
    float4 a0 = *(const float4*)ap,       a1 = *(const float4*)(ap + 4);
    float4 b0 = *(const float4*)bp,       b1 = *(const float4*)(bp + 4);
    *(half8*)&Al[0][sr * PSTR + sc] = cvt8(a0, a1);
    *(half8*)&Bl[0][sr * PSTR + sc] = cvt8(b0, b1);
    a0 = *(const float4*)(ap + 32); a1 = *(const float4*)(ap + 36);
    b0 = *(const float4*)(bp + 32); b1 = *(const float4*)(bp + 36);
    lds_barrier();

    // invariant entering iter kt: buf[p] = tile kt, regs = tile kt+32
#pragma unroll 2
    for (int kt = 0; kt < HID_; kt += 32) {
        const int p = (kt >> 5) & 1;

        // issue tile kt+64 loads: consumed one FULL iteration later (the
        // raw barrier below does not drain vmcnt).
        float4 na0 = a0, na1 = a1, nb0 = b0, nb1 = b1;
        if (kt + 64 < HID_) {
            na0 = *(const float4*)(ap + kt + 64);
            na1 = *(const float4*)(ap + kt + 68);
            nb0 = *(const float4*)(bp + kt + 64);
            nb1 = *(const float4*)(bp + kt + 68);
        }

        // frag reads from current buffer
        half8 af[4], bfm[2];
#pragma unroll
        for (int i = 0; i < 4; i++)
            af[i] = *(const half8*)(&Al[p][(wm * 64 + i * 16 + l15) * PSTR + quad * 8]);
#pragma unroll
        for (int j = 0; j < 2; j++)
            bfm[j] = *(const half8*)(&Bl[p][(wn * 32 + j * 16 + l15) * PSTR + quad * 8]);

        // stage tile kt+32 (regs loaded last iter; per-reg vmcnt wait only)
        if (kt + 32 < HID_) {
            *(half8*)&Al[p ^ 1][sr * PSTR + sc] = cvt8(a0, a1);
            *(half8*)&Bl[p ^ 1][sr * PSTR + sc] = cvt8(b0, b1);
        }

#pragma unroll
        for (int i = 0; i < 4; i++)
#pragma unroll
            for (int j = 0; j < 2; j++)
                acc[i][j] = __builtin_amdgcn_mfma_f32_16x16x32_f16(
                    af[i], bfm[j], acc[i][j], 0, 0, 0);

        lds_barrier();
        a0 = na0; a1 = na1; b0 = nb0; b1 = nb1;
    }

    const int isQ = (bz == 0);
#pragma unroll
    for (int j = 0; j < 2; j++) {
        int col = n0 + wn * 32 + j * 16 + l15;
        float bv = bias[col];
        int h = col >> 6, d = col & 63, p = d >> 3, jj = d & 7;
#pragma unroll
        for (int i = 0; i < 4; i++) {
            int row = m0 + wm * 64 + i * 16 + quad * 4;
            int bb = row >> 10, ss = row & 1023;   // tiles never straddle 1024
            long base;
            if (isQ)
                base = ((((long)(bb * NH_ + h) * 64 + (ss >> 4)) * 8 + p) * 16
                        + (ss & 15)) * 8 + jj;
            else
                base = (((long)(bb * NH_ + h) * 8 + p) * 1024 + ss) * 8 + jj;
            // both layouts advance by 8 elements per +1 row
#pragma unroll
            for (int r = 0; r < 4; r++)
                Co[base + r * 8] = (_Float16)(acc[i][j][r] + bv);
        }
    }
}

// ---------------------------------------------------------------------------
// MFMA attention, head-split z=4.  Fragment loads from the dense Q'/K'
// layouts. No-max softmax (scores bounded, single-inst exp2 + folded log2e),
// ONE barrier per head.  XCD swizzle: each chunk = 2 full (b,hz) groups so
// Q'/K' panels (~2 MB) stay in one XCD's L2.
// ---------------------------------------------------------------------------
__global__ __launch_bounds__(512) void attn_psum_f16(
    const _Float16* __restrict__ qb,   // Q' [B,NH,64,8,16,8]
    const _Float16* __restrict__ kb,   // K' [B,NH,8,S,8]
    const float* __restrict__ mask,    // [B,S]
    _Float16* __restrict__ P)          // 4 x [B,S,S] fp16 quarters
{
    // XCD-chunked swizzle over 1024 blocks (1024 % 8 == 0 -> bijective).
    const int f   = blockIdx.x + 64 * blockIdx.y + 256 * blockIdx.z;
    const int w2s = (f & 7) * 128 + (f >> 3);
    const int qt  = w2s & 63;          // q-tile (16 rows)
    const int b   = (w2s >> 6) & 3;
    const int hz  = w2s >> 8;          // head group 0..3

    const int q0   = qt * 16;
    const int tid  = threadIdx.x;
    const int w    = tid >> 6;         // wave 0..7
    const int lane = tid & 63;
    const int l15  = lane & 15;
    const int quad = lane >> 4;

    __shared__ float redS[2][16][8];

    const float SC = 0.125f * LOG2E;

    float mreg[8];
#pragma unroll
    for (int t = 0; t < 8; t++)
        mreg[t] = mask[b * S_ + t * 128 + w * 16 + l15] * LOG2E;

    f32x4 acc[8];
#pragma unroll
    for (int t = 0; t < 8; t++) acc[t] = (f32x4){0.f, 0.f, 0.f, 0.f};

    for (int ii = 0; ii < 4; ii++) {
        const int h = hz * 4 + ii;
        const _Float16* qh = qb + ((long)(b * NH_ + h) * 64 + qt) * 1024;
        const _Float16* kh = kb + (long)(b * NH_ + h) * 8192 * 8;

        // A frags: Q'[qt][plane=quad(+4)][l15][j] — dense wave loads
        half8 a0 = *(const half8*)(qh + quad * 128 + l15 * 8);
        half8 a1 = *(const half8*)(qh + (quad + 4) * 128 + l15 * 8);

        f32x4 s[8];
#pragma unroll
        for (int cc = 0; cc < 8; cc++) {
            const int key = cc * 128 + w * 16 + l15;
            half8 b0 = *(const half8*)(kh + (long)quad * 8192 + key * 8);
            half8 b1 = *(const half8*)(kh + (long)(quad + 4) * 8192 + key * 8);
            f32x4 c = (f32x4){0.f, 0.f, 0.f, 0.f};
            c = __builtin_amdgcn_mfma_f32_16x16x32_f16(a0, b0, c, 0, 0, 0);
            c = __builtin_amdgcn_mfma_f32_16x16x32_f16(a1, b1, c, 0, 0, 0);
            s[cc] = c;
        }

        // ---- exp2 + row-sum (no max pass; one barrier per head) ----
        const int p = ii & 1;
        float sm[4] = {0.f, 0.f, 0.f, 0.f};
#pragma unroll
        for (int t = 0; t < 8; t++)
#pragma unroll
            for (int r = 0; r < 4; r++) {
                float pr = fexp2(fmaf(s[t][r], SC, mreg[t]));
                s[t][r] = pr;
                sm[r] += pr;
            }
#pragma unroll
        for (int off = 1; off < 16; off <<= 1)
#pragma unroll
            for (int r = 0; r < 4; r++) sm[r] += __shfl_xor(sm[r], off);
        if (l15 == 0)
#pragma unroll
            for (int r = 0; r < 4; r++) redS[p][quad * 4 + r][w] = sm[r];
        __syncthreads();

#pragma unroll
        for (int r = 0; r < 4; r++) {
            float4 v0 = *(float4*)&redS[p][quad * 4 + r][0];
            float4 v1 = *(float4*)&redS[p][quad * 4 + r][4];
            float tot = (v0.x + v0.y + v0.z + v0.w) + (v1.x + v1.y + v1.z + v1.w);
            float inv = 1.f / tot;
#pragma unroll
            for (int t = 0; t < 8; t++) acc[t][r] += s[t][r] * inv;
        }
    }

    _Float16* prow = P + (long)hz * ((long)B_ * S_ * S_) + (long)(b * S_ + q0) * S_;
#pragma unroll
    for (int t = 0; t < 8; t++)
#pragma unroll
        for (int r = 0; r < 4; r++) {
            int row = quad * 4 + r;
            prow[(long)row * S_ + t * 128 + w * 16 + l15] = (_Float16)acc[t][r];
        }
}

// ---------------------------------------------------------------------------
// vt_combine: y==0 -> psum = P0+P1+P2+P3 (2048 x-blocks)
//             y==1 -> Vt[b,h,s] = (fp16) V[b,s,h]  (4096 x-blocks)
// ---------------------------------------------------------------------------
__global__ __launch_bounds__(256) void vt_combine(
    const _Float16* __restrict__ P, _Float16* __restrict__ o,
    const float* __restrict__ V, _Float16* __restrict__ Vt)
{
    __shared__ float t[32][33];
    if (blockIdx.y == 0) {
        if (blockIdx.x >= 2048) return;
        const long QS = (long)B_ * S_ * S_;
        long i = (long)(blockIdx.x * 256 + threadIdx.x) * 8;
        half8 a = *(const half8*)(P + i);
        half8 b = *(const half8*)(P + QS + i);
        half8 c = *(const half8*)(P + 2 * QS + i);
        half8 d = *(const half8*)(P + 3 * QS + i);
        half8 r;
#pragma unroll
        for (int e = 0; e < 8; e++)
            r[e] = (_Float16)((float)a[e] + (float)b[e] + (float)c[e] + (float)d[e]);
        *(half8*)(o + i) = r;
    } else {
        const int x  = blockIdx.x;
        const int b  = x >> 10;
        const int s0 = ((x >> 5) & 31) * 32;
        const int h0 = (x & 31) * 32;
        const int tx = threadIdx.x & 31, ty = threadIdx.x >> 5;
#pragma unroll
        for (int rr = 0; rr < 4; rr++) {
            int s = s0 + ty + rr * 8;
            t[ty + rr * 8][tx] = V[((long)b * S_ + s) * HID_ + h0 + tx];
        }
        __syncthreads();
#pragma unroll
        for (int rr = 0; rr < 4; rr++) {
            int h = h0 + ty + rr * 8;
            Vt[((long)b * HID_ + h) * S_ + s0 + tx] = (_Float16)t[tx][ty + rr * 8];
        }
    }
}

// ---------------------------------------------------------------------------
// PV GEMM: out = (psum @ Vt^T) / NH, fp16 MFMA, fp32 out.  128m x 64n tile,
// 256 thr = 4 waves (2m x 2n), BK=32, raw-barrier depth-2 pipeline.
// XCD swizzle: 2 XCDs per batch; A panel (1 MB) + Vt (2 MB) fit one L2.
// ---------------------------------------------------------------------------
__global__ __launch_bounds__(256) void pv_f16(
    const _Float16* __restrict__ Pc,   // [B,S,S] fp16 (combined psum)
    const _Float16* __restrict__ Vt,   // [B,HID,S] fp16
    float* __restrict__ out)           // [B,S,HID] fp32
{
    const int f   = blockIdx.x + 16 * blockIdx.y + 128 * blockIdx.z;
    const int xcd = f & 7, ii = f >> 3;
    const int bx  = ii & 15;
    const int by  = (ii >> 4) + ((xcd & 1) << 2);
    const int b   = xcd >> 1;

    const _Float16* A  = Pc + (long)b * S_ * S_;
    const _Float16* Bm = Vt + (long)b * HID_ * S_;

    __shared__ _Float16 Al[2][128 * PSTR];  // 2 x 10 KB
    __shared__ _Float16 Bl[2][64 * PSTR];   // 2 x 5 KB

    const int tid  = threadIdx.x;
    const int wv   = tid >> 6;
    const int lane = tid & 63;
    const int l15  = lane & 15;
    const int quad = lane >> 4;
    const int wm   = wv & 1, wn = wv >> 1;
    const int m0   = by * 128, n0 = bx * 64;
    const int sr   = tid >> 2;                       // 0..63
    const int sc   = (tid & 3) * 8;

    const _Float16* ap0 = A  + (long)(m0 + sr) * S_ + sc;
    const _Float16* ap1 = A  + (long)(m0 + 64 + sr) * S_ + sc;
    const _Float16* bp0 = Bm + (long)(n0 + sr) * S_ + sc;

    f32x4 acc[4][2];
#pragma unroll
    for (int i = 0; i < 4; i++)
#pragma unroll
        for (int j = 0; j < 2; j++) acc[i][j] = (f32x4){0.f, 0.f, 0.f, 0.f};

    // ---- prologue: tile 0 -> LDS buf0; tile 1 -> regs ----
    half8 ca0 = *(const half8*)(ap0);
    half8 ca1 = *(const half8*)(ap1);
    half8 cb0 = *(const half8*)(bp0);
    *(half8*)&Al[0][sr * PSTR + sc] = ca0;
    *(half8*)&Al[0][(64 + sr) * PSTR + sc] = ca1;
    *(half8*)&Bl[0][sr * PSTR + sc] = cb0;
    ca0 = *(const half8*)(ap0 + 32);
    ca1 = *(const half8*)(ap1 + 32);
    cb0 = *(const half8*)(bp0 + 32);
    lds_barrier();

    // invariant entering iter kt: buf[p] = tile kt, regs = tile kt+32
#pragma unroll 2
    for (int kt = 0; kt < S_; kt += 32) {
        const int p = (kt >> 5) & 1;

        half8 na0 = ca0, na1 = ca1, nb0 = cb0;
        if (kt + 64 < S_) {
            na0 = *(const half8*)(ap0 + kt + 64);
            na1 = *(const half8*)(ap1 + kt + 64);
            nb0 = *(const half8*)(bp0 + kt + 64);
        }

        half8 af[4], bfm[2];
#pragma unroll
        for (int i = 0; i < 4; i++)
            af[i] = *(const half8*)(&Al[p][(wm * 64 + i * 16 + l15) * PSTR + quad * 8]);
#pragma unroll
        for (int j = 0; j < 2; j++)
            bfm[j] = *(const half8*)(&Bl[p][(wn * 32 + j * 16 + l15) * PSTR + quad * 8]);

        if (kt + 32 < S_) {
            *(half8*)&Al[p ^ 1][sr * PSTR + sc] = ca0;
            *(half8*)&Al[p ^ 1][(64 + sr) * PSTR + sc] = ca1;
            *(half8*)&Bl[p ^ 1][sr * PSTR + sc] = cb0;
        }

#pragma unroll
        for (int i = 0; i < 4; i++)
#pragma unroll
            for (int j = 0; j < 2; j++)
                acc[i][j] = __builtin_amdgcn_mfma_f32_16x16x32_f16(
                    af[i], bfm[j], acc[i][j], 0, 0, 0);

        lds_barrier();
        ca0 = na0; ca1 = na1; cb0 = nb0;
    }

    const float alpha = 1.f / NH_;
#pragma unroll
    for (int i = 0; i < 4; i++) {
        int row = m0 + wm * 64 + i * 16 + quad * 4;
#pragma unroll
        for (int j = 0; j < 2; j++) {
            int col = n0 + wn * 32 + j * 16 + l15;
#pragma unroll
            for (int r = 0; r < 4; r++)
                out[(long)(b * S_ + row + r) * HID_ + col] = acc[i][j][r] * alpha;
        }
    }
}

// ---------------------------------------------------------------------------
extern "C" void kernel_launch(void* const* d_in, const int* in_sizes, int n_in,
                              void* d_out, int out_size, void* d_ws, size_t ws_size,
                              hipStream_t stream)
{
    const float* mask  = (const float*)d_in[0];
    const float* query = (const float*)d_in[1];
    const float* key   = (const float*)d_in[2];
    const float* value = (const float*)d_in[3];
    const float* Wq    = (const float*)d_in[4];
    const float* bq    = (const float*)d_in[5];
    const float* Wk    = (const float*)d_in[6];
    const float* bk    = (const float*)d_in[7];
    float* out = (float*)d_out;

    // Workspace (48 MiB, hand-offs between SEQUENTIAL dispatches only):
    //  [ 0, 8M): qbuf (Q' proj out)  -> after attn: Vt
    //  [ 8,16M): kbuf (K' proj out)  -> after attn: psum (combine out)
    //  [16,48M): P quarters (4 x 8M)
    char* ws = (char*)d_ws;
    const long MB = 1l << 20;
    _Float16* qbuf = (_Float16*)(ws);
    _Float16* kbuf = (_Float16*)(ws + 8 * MB);
    _Float16* Pq   = (_Float16*)(ws + 16 * MB);
    _Float16* Vt   = (_Float16*)(ws);             // reuses qbuf after attn
    _Float16* psum = (_Float16*)(ws + 8 * MB);    // reuses kbuf after attn

    // 1) fused q/k projection (fp32 in, inline cvt, fragment-layout fp16 out)
    proj_qk_f16<<<dim3(HID_ / 128, (B_ * S_) / 128, 2), dim3(512), 0, stream>>>(
        query, Wq, bq, qbuf, key, Wk, bk, kbuf);

    // 2) attention, head-split z=4 -> P quarters
    attn_psum_f16<<<dim3(S_ / 16, B_, 4), dim3(512), 0, stream>>>(
        qbuf, kbuf, mask, Pq);

    // 3) fused: sum the 4 quarters -> psum ; V -> fp16 transpose -> Vt
    vt_combine<<<dim3(4096, 2), dim3(256), 0, stream>>>(Pq, psum, value, Vt);

    // 4) out = psum @ Vt^T / NH
    pv_f16<<<dim3(HID_ / 64, S_ / 128, B_), dim3(256), 0, stream>>>(psum, Vt, out);
}